// Round 13
// baseline (527.932 us; speedup 1.0000x reference)
//
#include <hip/hip_runtime.h>

#define D_DIM 1024
#define N_INNER 4096
#define NEXP 8
#define T_TOK 8192
#define EPSV 1e-6f

typedef __attribute__((ext_vector_type(4))) float f32x4;
typedef __bf16 bf16x8 __attribute__((ext_vector_type(8)));

typedef const __attribute__((address_space(1))) void gvoid_t;
typedef __attribute__((address_space(3))) void lvoid_t;

#define VMCNT(n) asm volatile("s_waitcnt vmcnt(" #n ")" ::: "memory")
#define SCHEDB() __builtin_amdgcn_sched_barrier(0)

static __device__ __forceinline__ unsigned short f2bf(float f) {
    unsigned int u = __float_as_uint(f);
    u = u + 0x7fffu + ((u >> 16) & 1u);   // round-to-nearest-even
    return (unsigned short)(u >> 16);
}

// ---------------- gating: one wave per token ----------------
__global__ __launch_bounds__(256) void k_gate(const float* __restrict__ x,
                                              const float* __restrict__ Wg,
                                              const float* __restrict__ bg,
                                              int* __restrict__ top1,
                                              float* __restrict__ score) {
    __shared__ float wgT[NEXP * D_DIM];
    int tid = threadIdx.x;
    for (int i = tid; i < NEXP * D_DIM; i += 256)
        wgT[(i & 7) * D_DIM + (i >> 3)] = Wg[i];
    __syncthreads();

    int wid = tid >> 6, lane = tid & 63;
    int t = blockIdx.x * 4 + wid;
    float acc[8] = {0.f, 0.f, 0.f, 0.f, 0.f, 0.f, 0.f, 0.f};
    const float* xp = x + (size_t)t * D_DIM + lane;
    for (int c = 0; c < D_DIM / 64; ++c) {
        float xv = xp[c * 64];
#pragma unroll
        for (int e = 0; e < 8; ++e) acc[e] += xv * wgT[e * D_DIM + c * 64 + lane];
    }
#pragma unroll
    for (int e = 0; e < 8; ++e) {
        float v = acc[e];
        for (int o = 32; o; o >>= 1) v += __shfl_xor(v, o);
        acc[e] = v;
    }
    if (lane == 0) {
        float mx = -1e30f;
#pragma unroll
        for (int e = 0; e < 8; ++e) { acc[e] += bg[e]; mx = fmaxf(mx, acc[e]); }
        float p[8], s = 0.f;
#pragma unroll
        for (int e = 0; e < 8; ++e) { p[e] = expf(acc[e] - mx); s += p[e]; }
        int best = 0; float bv = acc[0];
#pragma unroll
        for (int e = 1; e < 8; ++e) if (acc[e] > bv) { bv = acc[e]; best = e; }
        top1[t]  = best;
        score[t] = p[best] / s;
    }
}

// ---------------- deterministic per-expert reduce + BM=128 tile table ----------------
__global__ void k_meta(const int* __restrict__ top1, const float* __restrict__ score,
                       int* __restrict__ mi, float* __restrict__ mf) {
    int wid = threadIdx.x >> 6, lane = threadIdx.x & 63;
    float s[8] = {0.f, 0.f, 0.f, 0.f, 0.f, 0.f, 0.f, 0.f};
    int   c[8] = {0, 0, 0, 0, 0, 0, 0, 0};
    for (int it = 0; it < T_TOK / 512; ++it) {
        int t = wid * (T_TOK / 8) + it * 64 + lane;
        int e = top1[t]; float sc = score[t];
#pragma unroll
        for (int k = 0; k < 8; ++k) {
            bool m = (e == k);
            s[k] += m ? sc : 0.f;
            c[k] += m ? 1 : 0;
        }
    }
#pragma unroll
    for (int k = 0; k < 8; ++k)
        for (int o = 32; o; o >>= 1) { s[k] += __shfl_down(s[k], o); c[k] += __shfl_down(c[k], o); }
    __shared__ float ss[8][8];
    __shared__ int   cc[8][8];
    if (lane == 0) {
#pragma unroll
        for (int k = 0; k < 8; ++k) { ss[wid][k] = s[k]; cc[wid][k] = c[k]; }
    }
    __syncthreads();
    if (threadIdx.x == 0) {
        int off = 0, nt = 0;
        for (int e = 0; e < 8; ++e) {
            int   ct = 0; float st = 0.f;
#pragma unroll
            for (int w2 = 0; w2 < 8; ++w2) { ct += cc[w2][e]; st += ss[w2][e]; }
            mi[16 + e] = off;                       // scatter cursor
            mf[e]      = st;
            mf[8 + e]  = (float)T_TOK / (st + EPSV);
            int end = off + ct;
            for (int m = off; m < end; m += 128) {  // BM=128 tiles
                mi[64  + nt] = e;
                mi[144 + nt] = m;
                mi[224 + nt] = end;
                nt++;
            }
            off = end;
        }
        mi[0] = nt;
    }
}

// ---------------- scatter tokens to expert-contiguous slots ----------------
__global__ __launch_bounds__(256) void k_scatter(const int* __restrict__ top1,
                                                 const float* __restrict__ score,
                                                 int* __restrict__ mi,
                                                 const float* __restrict__ mf,
                                                 int* __restrict__ perm,
                                                 float* __restrict__ coef) {
    int t = blockIdx.x * 256 + threadIdx.x;
    if (t >= T_TOK) return;
    int e = top1[t];
    int slot = atomicAdd(&mi[16 + e], 1);
    perm[slot] = t;
    coef[slot] = score[t] * mf[8 + e];
}

// ---------------- gather x rows into bf16, slot order ----------------
__global__ __launch_bounds__(256) void k_gatherX(const float* __restrict__ x,
                                                 const int* __restrict__ perm,
                                                 unsigned short* __restrict__ Xg) {
    int i = blockIdx.x * 256 + threadIdx.x;
    int slot = i >> 7, ch = (i & 127) * 8;
    int t = perm[slot];
    const float4* px = (const float4*)(x + (size_t)t * D_DIM + ch);
    float4 a = px[0], b = px[1];
    union { unsigned short u[8]; uint4 v; } o;
    o.u[0] = f2bf(a.x); o.u[1] = f2bf(a.y); o.u[2] = f2bf(a.z); o.u[3] = f2bf(a.w);
    o.u[4] = f2bf(b.x); o.u[5] = f2bf(b.y); o.u[6] = f2bf(b.z); o.u[7] = f2bf(b.w);
    *(uint4*)(Xg + (size_t)slot * D_DIM + ch) = o.v;
}

// ---------------- transpose + cast weights: [E][R][C] f32 -> [E][C][R] bf16 ----------------
__global__ __launch_bounds__(256) void k_transp(const float* __restrict__ W,
                                                unsigned short* __restrict__ Wt,
                                                int R, int C) {
    __shared__ float tile[64][65];
    int e  = blockIdx.z;
    int c0 = blockIdx.x * 64, r0 = blockIdx.y * 64;
    int tr = threadIdx.x >> 6, tc = threadIdx.x & 63;
    const float* Win = W + ((size_t)e * R + r0) * C + c0;
#pragma unroll
    for (int it = 0; it < 16; ++it) {
        int r = it * 4 + tr;
        tile[r][tc] = Win[(size_t)r * C + tc];
    }
    __syncthreads();
    unsigned short* Wo = Wt + ((size_t)e * C + c0) * R + r0;
#pragma unroll
    for (int it = 0; it < 16; ++it) {
        int r = it * 4 + tr;
        Wo[(size_t)r * R + tc] = f2bf(tile[tc][r]);
    }
}

// ====== HYBRID grouped GEMM: 128x128, BK=32; B via LDS (4-buf counted), A direct-to-reg ======
// 256 thr = 4 waves (2M x 2N), wave-out 64x64.  LDS = 4 x 8KB B-buffers (32 KB) -> 3 blocks/CU
// (VGPR-bound, __launch_bounds__(256,3)).  LDS-staged bytes HALVED vs R11 (B only: 576 MB/GEMM)
// at the same 3-bpc delivery point; A fragments are per-lane 16B vector loads (R10-verified
// layout), prefetched 2 K-steps ahead, served by L2/L3 (A panels L3-resident).
// Per phase p: { VMCNT(6) [drains B(p)+af(p); keeps B(p+2)? no: keeps B(p+2),af(p+1)] ->
//   barrier -> stage_B(p+3) -> ds_read bfv(buf p%4) -> lgkm0 -> MFMA(af_cur) -> load af(p+2) }
// Prologue waits: VMCNT(8) at p=0,1; steady VMCNT(6); last 3 phases VMCNT(0).
// MODE 0: H = relu(A@B^T) bf16.  MODE 1: unsafeAtomicAdd(out[perm[row]], coef*acc), split-K 2.
template <int MODE>
__global__ __launch_bounds__(256, 3) void k_moe_gemm(const unsigned short* __restrict__ A,
                                                     const unsigned short* __restrict__ B,
                                                     void* __restrict__ Cout,
                                                     const int* __restrict__ mi,
                                                     const int* __restrict__ perm,
                                                     const float* __restrict__ coef,
                                                     const int KSTRIDE, const int N_TOT,
                                                     const int NT) {
    __shared__ char lds[32768];
    const int nt = mi[0];
    const int wg = blockIdx.x;
    const int xcd = wg & 7;
    const int j = wg >> 3;
    int ti, n0, kOff;
    if (MODE == 0) {            // N=4096: 32 n-tiles, 4 per XCD
        ti = j >> 2; n0 = (xcd * 4 + (j & 3)) * 128; kOff = 0;
    } else {                    // N=1024: 8 n-tiles x 2 K-halves = 16 groups, 2 per XCD
        ti = j >> 1; int g = xcd * 2 + (j & 1);
        n0 = (g >> 1) * 128; kOff = (g & 1) * (NT * 32);
    }
    if (ti >= nt) return;
    const int e    = mi[64 + ti];
    const int m0   = mi[144 + ti];
    const int mend = mi[224 + ti];
    const int tid  = threadIdx.x;
    const int w    = tid >> 6, l = tid & 63;
    const int wr   = w >> 1, wc = w & 1;
    const int fr   = l & 15, fq = l >> 4;
    const unsigned short* Bexp = B + (size_t)e * N_TOT * KSTRIDE;

    // ---- B staging (LDS path, R11-proven swizzle pair) ----
    const int gch  = (l & 3) ^ ((l >> 3) & 3);     // inverse-swizzled 16B chunk
    const int brow = w * 16 + (l >> 2);            // 0..63 within each 64-row half
    const unsigned short* bB0 = Bexp + (size_t)(n0 + brow) * KSTRIDE + kOff + gch * 8;
    const unsigned short* bB1 = Bexp + (size_t)(n0 + 64 + brow) * KSTRIDE + kOff + gch * 8;
    const int sdst = w * 1024 + l * 16;

    auto stageB = [&](int p) {
        if (p < NT) {
            char* bb = lds + (p & 3) * 8192;
            __builtin_amdgcn_global_load_lds((gvoid_t*)(bB0 + p * 32), (lvoid_t*)(bb + sdst),        16, 0, 0);
            __builtin_amdgcn_global_load_lds((gvoid_t*)(bB1 + p * 32), (lvoid_t*)(bb + 4096 + sdst), 16, 0, 0);
        }
    };

    // ---- A fragment pointers (direct per-lane 16B loads; R10-verified layout) ----
    const unsigned short* aF[4];
#pragma unroll
    for (int m = 0; m < 4; ++m) {
        int r = m0 + wr * 64 + m * 16 + fr;
        if (r > T_TOK - 1) r = T_TOK - 1;          // clamp tail rows (stores masked)
        aF[m] = A + (size_t)r * KSTRIDE + kOff + fq * 8;
    }
    bf16x8 afA[4], afB[4];
#define LOAD_AFA(P) { _Pragma("unroll") for (int m = 0; m < 4; ++m) afA[m] = *(const bf16x8*)(aF[m] + (P) * 32); }
#define LOAD_AFB(P) { _Pragma("unroll") for (int m = 0; m < 4; ++m) afB[m] = *(const bf16x8*)(aF[m] + (P) * 32); }

    f32x4 acc[4][4];
#pragma unroll
    for (int m = 0; m < 4; ++m)
#pragma unroll
        for (int n = 0; n < 4; ++n) acc[m][n] = (f32x4){0.f, 0.f, 0.f, 0.f};

    const int pos = (fq ^ ((fr >> 1) & 3)) * 16;   // B read-side swizzle

    // prologue: afA(0), B(0), afB(1), B(1), B(2)  [oldest->newest]
    LOAD_AFA(0);
    stageB(0);
    LOAD_AFB(1);
    stageB(1); stageB(2);

    for (int p = 0; p < NT; p += 2) {
        // ---- phase p (even): consume afA, buf p ----
        if (p < 2)            { VMCNT(8); }
        else if (p < NT - 3)  { VMCNT(6); }
        else                  { VMCNT(0); }
        SCHEDB();
        __builtin_amdgcn_s_barrier();              // buf p%4 fully valid for all waves
        stageB(p + 3);
        {
            const char* buf = lds + (p & 3) * 8192;
            bf16x8 bfv[4];
#pragma unroll
            for (int n = 0; n < 4; ++n)
                bfv[n] = *(const bf16x8*)(buf + (wc * 64 + n * 16 + fr) * 64 + pos);
            asm volatile("s_waitcnt lgkmcnt(0)" ::: "memory");
            SCHEDB();
            __builtin_amdgcn_s_setprio(1);
#pragma unroll
            for (int m = 0; m < 4; ++m)
#pragma unroll
                for (int n = 0; n < 4; ++n)
                    acc[m][n] = __builtin_amdgcn_mfma_f32_16x16x32_bf16(afA[m], bfv[n], acc[m][n], 0, 0, 0);
            __builtin_amdgcn_s_setprio(0);
            SCHEDB();
        }
        if (p + 2 < NT) LOAD_AFA(p + 2);           // refill afA after its consumption

        // ---- phase p+1 (odd): consume afB, buf p+1 ----
        if (p + 1 < 2)            { VMCNT(8); }
        else if (p + 1 < NT - 3)  { VMCNT(6); }
        else                      { VMCNT(0); }
        SCHEDB();
        __builtin_amdgcn_s_barrier();
        stageB(p + 4);
        {
            const char* buf = lds + ((p + 1) & 3) * 8192;
            bf16x8 bfv[4];
#pragma unroll
            for (int n = 0; n < 4; ++n)
                bfv[n] = *(const bf16x8*)(buf + (wc * 64 + n * 16 + fr) * 64 + pos);
            asm volatile("s_waitcnt lgkmcnt(0)" ::: "memory");
            SCHEDB();
            __builtin_amdgcn_s_setprio(1);
#pragma unroll
            for (int m = 0; m < 4; ++m)
#pragma unroll
                for (int n = 0; n < 4; ++n)
                    acc[m][n] = __builtin_amdgcn_mfma_f32_16x16x32_bf16(afB[m], bfv[n], acc[m][n], 0, 0, 0);
            __builtin_amdgcn_s_setprio(0);
            SCHEDB();
        }
        if (p + 3 < NT) LOAD_AFB(p + 3);           // refill afB
    }

    // ---- epilogue ----
    if (MODE == 0) {
        unsigned short* H = (unsigned short*)Cout;
#pragma unroll
        for (int m = 0; m < 4; ++m) {
            int rb = m0 + wr * 64 + m * 16 + fq * 4;
#pragma unroll
            for (int r = 0; r < 4; ++r) {
                int row = rb + r;
                if (row < mend) {
#pragma unroll
                    for (int n = 0; n < 4; ++n) {
                        int col = n0 + wc * 64 + n * 16 + fr;
                        float v = fmaxf(acc[m][n][r], 0.f);
                        H[(size_t)row * N_TOT + col] = f2bf(v);
                    }
                }
            }
        }
    } else {
        float* O = (float*)Cout;
#pragma unroll
        for (int m = 0; m < 4; ++m) {
            int rb = m0 + wr * 64 + m * 16 + fq * 4;
#pragma unroll
            for (int r = 0; r < 4; ++r) {
                int row = rb + r;
                if (row < mend) {
                    int   tkn = perm[row];
                    float cf  = coef[row];
#pragma unroll
                    for (int n = 0; n < 4; ++n) {
                        int col = n0 + wc * 64 + n * 16 + fr;
                        unsafeAtomicAdd(&O[(size_t)tkn * N_TOT + col], cf * acc[m][n][r]);
                    }
                }
            }
        }
    }
}

extern "C" void kernel_launch(void* const* d_in, const int* in_sizes, int n_in,
                              void* d_out, int out_size, void* d_ws, size_t ws_size,
                              hipStream_t stream) {
    const float* x  = (const float*)d_in[0];
    const float* Wg = (const float*)d_in[1];
    const float* bg = (const float*)d_in[2];
    const float* W1 = (const float*)d_in[3];
    const float* W2 = (const float*)d_in[4];

    char* ws = (char*)d_ws;
    int*   mi    = (int*)ws;
    float* mf    = (float*)(ws + 2048);
    int*   top1  = (int*)(ws + 4096);
    float* score = (float*)(ws + 36864);
    int*   perm  = (int*)(ws + 69632);
    float* coef  = (float*)(ws + 102400);
    unsigned short* Xg = (unsigned short*)(ws + 135168);     // 8192 x 1024 bf16
    unsigned short* H  = (unsigned short*)(ws + 16912384);   // 8192 x 4096 bf16
    unsigned short* Wt = (unsigned short*)(ws + 84021248);   // 8 x 4096 x 1024 bf16 (shared)

    // zero d_out: GEMM2 combines split-K halves with 2-way commutative atomic adds
    hipMemsetAsync(d_out, 0, (size_t)out_size * sizeof(float), stream);

    k_gate<<<dim3(T_TOK / 4), dim3(256), 0, stream>>>(x, Wg, bg, top1, score);
    k_meta<<<dim3(1), dim3(512), 0, stream>>>(top1, score, mi, mf);
    k_scatter<<<dim3(T_TOK / 256), dim3(256), 0, stream>>>(top1, score, mi, mf, perm, coef);
    k_gatherX<<<dim3(T_TOK * 128 / 256), dim3(256), 0, stream>>>(x, perm, Xg);

    // W1: [8][1024][4096] f32 -> Wt [8][4096][1024] bf16
    k_transp<<<dim3(N_INNER / 64, D_DIM / 64, NEXP), dim3(256), 0, stream>>>(W1, Wt, D_DIM, N_INNER);
    // H = relu(Xg @ W1t), K=1024 (NT=32).  Grid: 8 xcd x 4 n x 72 ti = 2304 blocks.
    k_moe_gemm<0><<<dim3(2304), dim3(256), 0, stream>>>(
        Xg, Wt, (void*)H, mi, perm, coef, D_DIM, N_INNER, 32);
    // W2: [8][4096][1024] f32 -> Wt [8][1024][4096] bf16
    k_transp<<<dim3(D_DIM / 64, N_INNER / 64, NEXP), dim3(256), 0, stream>>>(W2, Wt, N_INNER, D_DIM);
    // out += coef * (H @ W2t), split-K 2 (NT=64 per half).  Grid: 8 xcd x 2 g x 72 ti = 1152.
    k_moe_gemm<1><<<dim3(1152), dim3(256), 0, stream>>>(
        H, Wt, d_out, mi, perm, coef, N_INNER, D_DIM, 64);
}

// Round 14
// 385.353 us; speedup vs baseline: 1.3700x; 1.3700x over previous
//
#include <hip/hip_runtime.h>

#define D_DIM 1024
#define N_INNER 4096
#define NEXP 8
#define T_TOK 8192
#define EPSV 1e-6f

typedef __attribute__((ext_vector_type(4))) float f32x4;
typedef __bf16 bf16x8 __attribute__((ext_vector_type(8)));

typedef const __attribute__((address_space(1))) void gvoid_t;
typedef __attribute__((address_space(3))) void lvoid_t;

#define VMCNT(n) asm volatile("s_waitcnt vmcnt(" #n ")" ::: "memory")
#define SCHEDB() __builtin_amdgcn_sched_barrier(0)

static __device__ __forceinline__ unsigned short f2bf(float f) {
    unsigned int u = __float_as_uint(f);
    u = u + 0x7fffu + ((u >> 16) & 1u);   // round-to-nearest-even
    return (unsigned short)(u >> 16);
}

// ---------------- gating: one wave per token ----------------
__global__ __launch_bounds__(256) void k_gate(const float* __restrict__ x,
                                              const float* __restrict__ Wg,
                                              const float* __restrict__ bg,
                                              int* __restrict__ top1,
                                              float* __restrict__ score) {
    __shared__ float wgT[NEXP * D_DIM];
    int tid = threadIdx.x;
    for (int i = tid; i < NEXP * D_DIM; i += 256)
        wgT[(i & 7) * D_DIM + (i >> 3)] = Wg[i];
    __syncthreads();

    int wid = tid >> 6, lane = tid & 63;
    int t = blockIdx.x * 4 + wid;
    float acc[8] = {0.f, 0.f, 0.f, 0.f, 0.f, 0.f, 0.f, 0.f};
    const float* xp = x + (size_t)t * D_DIM + lane;
    for (int c = 0; c < D_DIM / 64; ++c) {
        float xv = xp[c * 64];
#pragma unroll
        for (int e = 0; e < 8; ++e) acc[e] += xv * wgT[e * D_DIM + c * 64 + lane];
    }
#pragma unroll
    for (int e = 0; e < 8; ++e) {
        float v = acc[e];
        for (int o = 32; o; o >>= 1) v += __shfl_xor(v, o);
        acc[e] = v;
    }
    if (lane == 0) {
        float mx = -1e30f;
#pragma unroll
        for (int e = 0; e < 8; ++e) { acc[e] += bg[e]; mx = fmaxf(mx, acc[e]); }
        float p[8], s = 0.f;
#pragma unroll
        for (int e = 0; e < 8; ++e) { p[e] = expf(acc[e] - mx); s += p[e]; }
        int best = 0; float bv = acc[0];
#pragma unroll
        for (int e = 1; e < 8; ++e) if (acc[e] > bv) { bv = acc[e]; best = e; }
        top1[t]  = best;
        score[t] = p[best] / s;
    }
}

// ---------------- deterministic per-expert reduce + BM=128 tile table ----------------
__global__ void k_meta(const int* __restrict__ top1, const float* __restrict__ score,
                       int* __restrict__ mi, float* __restrict__ mf) {
    int wid = threadIdx.x >> 6, lane = threadIdx.x & 63;
    float s[8] = {0.f, 0.f, 0.f, 0.f, 0.f, 0.f, 0.f, 0.f};
    int   c[8] = {0, 0, 0, 0, 0, 0, 0, 0};
    for (int it = 0; it < T_TOK / 512; ++it) {
        int t = wid * (T_TOK / 8) + it * 64 + lane;
        int e = top1[t]; float sc = score[t];
#pragma unroll
        for (int k = 0; k < 8; ++k) {
            bool m = (e == k);
            s[k] += m ? sc : 0.f;
            c[k] += m ? 1 : 0;
        }
    }
#pragma unroll
    for (int k = 0; k < 8; ++k)
        for (int o = 32; o; o >>= 1) { s[k] += __shfl_down(s[k], o); c[k] += __shfl_down(c[k], o); }
    __shared__ float ss[8][8];
    __shared__ int   cc[8][8];
    if (lane == 0) {
#pragma unroll
        for (int k = 0; k < 8; ++k) { ss[wid][k] = s[k]; cc[wid][k] = c[k]; }
    }
    __syncthreads();
    if (threadIdx.x == 0) {
        int off = 0, nt = 0;
        for (int e = 0; e < 8; ++e) {
            int   ct = 0; float st = 0.f;
#pragma unroll
            for (int w2 = 0; w2 < 8; ++w2) { ct += cc[w2][e]; st += ss[w2][e]; }
            mi[16 + e] = off;                       // scatter cursor
            mf[e]      = st;
            mf[8 + e]  = (float)T_TOK / (st + EPSV);
            int end = off + ct;
            for (int m = off; m < end; m += 128) {  // BM=128 tiles
                mi[64  + nt] = e;
                mi[144 + nt] = m;
                mi[224 + nt] = end;
                nt++;
            }
            off = end;
        }
        mi[0] = nt;
    }
}

// ---------------- scatter tokens to expert-contiguous slots ----------------
__global__ __launch_bounds__(256) void k_scatter(const int* __restrict__ top1,
                                                 const float* __restrict__ score,
                                                 int* __restrict__ mi,
                                                 const float* __restrict__ mf,
                                                 int* __restrict__ perm,
                                                 float* __restrict__ coef) {
    int t = blockIdx.x * 256 + threadIdx.x;
    if (t >= T_TOK) return;
    int e = top1[t];
    int slot = atomicAdd(&mi[16 + e], 1);
    perm[slot] = t;
    coef[slot] = score[t] * mf[8 + e];
}

// ---------------- gather x rows into bf16, slot order ----------------
__global__ __launch_bounds__(256) void k_gatherX(const float* __restrict__ x,
                                                 const int* __restrict__ perm,
                                                 unsigned short* __restrict__ Xg) {
    int i = blockIdx.x * 256 + threadIdx.x;
    int slot = i >> 7, ch = (i & 127) * 8;
    int t = perm[slot];
    const float4* px = (const float4*)(x + (size_t)t * D_DIM + ch);
    float4 a = px[0], b = px[1];
    union { unsigned short u[8]; uint4 v; } o;
    o.u[0] = f2bf(a.x); o.u[1] = f2bf(a.y); o.u[2] = f2bf(a.z); o.u[3] = f2bf(a.w);
    o.u[4] = f2bf(b.x); o.u[5] = f2bf(b.y); o.u[6] = f2bf(b.z); o.u[7] = f2bf(b.w);
    *(uint4*)(Xg + (size_t)slot * D_DIM + ch) = o.v;
}

// ---------------- transpose + cast weights: [E][R][C] f32 -> [E][C][R] bf16 ----------------
__global__ __launch_bounds__(256) void k_transp(const float* __restrict__ W,
                                                unsigned short* __restrict__ Wt,
                                                int R, int C) {
    __shared__ float tile[64][65];
    int e  = blockIdx.z;
    int c0 = blockIdx.x * 64, r0 = blockIdx.y * 64;
    int tr = threadIdx.x >> 6, tc = threadIdx.x & 63;
    const float* Win = W + ((size_t)e * R + r0) * C + c0;
#pragma unroll
    for (int it = 0; it < 16; ++it) {
        int r = it * 4 + tr;
        tile[r][tc] = Win[(size_t)r * C + tc];
    }
    __syncthreads();
    unsigned short* Wo = Wt + ((size_t)e * C + c0) * R + r0;
#pragma unroll
    for (int it = 0; it < 16; ++it) {
        int r = it * 4 + tr;
        Wo[(size_t)r * R + tc] = f2bf(tile[tc][r]);
    }
}

// ====== grouped GEMM: 128x128 tile, BK=32, 3 LDS buffers, depth-2 counted prefetch ======
// 256 thr = 4 waves (2M x 2N), wave-out 64x64.  48 KB LDS -> 3 blocks/CU.
// Per kt: { VMCNT(4) [kt landed, kt+1 in flight] -> barrier -> stage(kt+2) -> 12x ds_read
//           -> lgkmcnt(0) -> MFMA }.  Measured optimum of the blocks/CU x depth tradeoff:
// delivery ~8.1 TB/s vs 2.3 GB mandatory staged traffic (R5/R11/R12 sweep).
// MODE 0: H = relu(A@B^T) bf16.  MODE 1: unsafeAtomicAdd(out[perm[row]], coef*acc) (split-K 2).
template <int MODE>
__global__ __launch_bounds__(256, 3) void k_moe_gemm(const unsigned short* __restrict__ A,
                                                     const unsigned short* __restrict__ B,
                                                     void* __restrict__ Cout,
                                                     const int* __restrict__ mi,
                                                     const int* __restrict__ perm,
                                                     const float* __restrict__ coef,
                                                     const int KSTRIDE, const int N_TOT,
                                                     const int NT) {
    __shared__ char lds[49152];
    const int nt = mi[0];
    const int wg = blockIdx.x;
    const int xcd = wg & 7;
    const int j = wg >> 3;
    int ti, n0, ktB;
    if (MODE == 0) {            // N=4096: 32 n-tiles, 4 per XCD
        ti = j >> 2; n0 = (xcd * 4 + (j & 3)) * 128; ktB = 0;
    } else {                    // N=1024: 8 n-tiles x 2 K-halves = 16 groups, 2 per XCD
        ti = j >> 1; int g = xcd * 2 + (j & 1);
        n0 = (g >> 1) * 128; ktB = (g & 1) * NT;
    }
    if (ti >= nt) return;
    const int e    = mi[64 + ti];
    const int m0   = mi[144 + ti];
    const int mend = mi[224 + ti];
    const int tid  = threadIdx.x;
    const int w    = tid >> 6, l = tid & 63;
    const int wr   = w >> 1, wc = w & 1;
    const int fr   = l & 15, fq = l >> 4;
    const unsigned short* Bexp = B + (size_t)e * N_TOT * KSTRIDE;

    const int gch  = (l & 3) ^ ((l >> 3) & 3);     // inverse-swizzled 16B chunk
    const int arow = w * 16 + (l >> 2);
    int ar0 = m0 + arow;      if (ar0 > T_TOK - 1) ar0 = T_TOK - 1;
    int ar1 = m0 + 64 + arow; if (ar1 > T_TOK - 1) ar1 = T_TOK - 1;
    const unsigned short* aB0 = A + (size_t)ar0 * KSTRIDE + ktB * 32 + gch * 8;
    const unsigned short* aB1 = A + (size_t)ar1 * KSTRIDE + ktB * 32 + gch * 8;
    const unsigned short* bB0 = Bexp + (size_t)(n0 + arow) * KSTRIDE + ktB * 32 + gch * 8;
    const unsigned short* bB1 = Bexp + (size_t)(n0 + 64 + arow) * KSTRIDE + ktB * 32 + gch * 8;
    const int sdst = w * 1024 + l * 16;

    auto stage = [&](int t) {
        char* bb = lds + (t % 3) * 16384;
        __builtin_amdgcn_global_load_lds((gvoid_t*)(aB0 + t * 32), (lvoid_t*)(bb + sdst),          16, 0, 0);
        __builtin_amdgcn_global_load_lds((gvoid_t*)(aB1 + t * 32), (lvoid_t*)(bb + 4096 + sdst),   16, 0, 0);
        __builtin_amdgcn_global_load_lds((gvoid_t*)(bB0 + t * 32), (lvoid_t*)(bb + 8192 + sdst),   16, 0, 0);
        __builtin_amdgcn_global_load_lds((gvoid_t*)(bB1 + t * 32), (lvoid_t*)(bb + 12288 + sdst),  16, 0, 0);
    };

    f32x4 acc[4][4];
#pragma unroll
    for (int m = 0; m < 4; ++m)
#pragma unroll
        for (int n = 0; n < 4; ++n) acc[m][n] = (f32x4){0.f, 0.f, 0.f, 0.f};

    const int pos = (fq ^ ((fr >> 1) & 3)) * 16;   // read-side swizzle

    // prologue: prefetch kt 0,1 (8 loads/thread in flight)
    stage(0); stage(1);

    for (int kt = 0; kt < NT; ++kt) {
        // outstanding on arrival: stage(kt) + stage(kt+1) = 8 (4 at last iter)
        if (kt < NT - 1) { VMCNT(4); } else { VMCNT(0); }
        SCHEDB();
        __builtin_amdgcn_s_barrier();              // buf kt fully valid for all waves
        if (kt + 2 < NT) stage(kt + 2);            // refill buf (kt+2)%3

        const char* buf = lds + (kt % 3) * 16384;
        bf16x8 af[4], bfv[4];
#pragma unroll
        for (int m = 0; m < 4; ++m)
            af[m] = *(const bf16x8*)(buf + (wr * 64 + m * 16 + fr) * 64 + pos);
#pragma unroll
        for (int n = 0; n < 4; ++n)
            bfv[n] = *(const bf16x8*)(buf + 8192 + (wc * 64 + n * 16 + fr) * 64 + pos);
        asm volatile("s_waitcnt lgkmcnt(0)" ::: "memory");
        SCHEDB();
        __builtin_amdgcn_s_setprio(1);
#pragma unroll
        for (int m = 0; m < 4; ++m)
#pragma unroll
            for (int n = 0; n < 4; ++n)
                acc[m][n] = __builtin_amdgcn_mfma_f32_16x16x32_bf16(af[m], bfv[n], acc[m][n], 0, 0, 0);
        __builtin_amdgcn_s_setprio(0);
        SCHEDB();
    }

    // ---- epilogue ----
    if (MODE == 0) {
        unsigned short* H = (unsigned short*)Cout;
#pragma unroll
        for (int m = 0; m < 4; ++m) {
            int rb = m0 + wr * 64 + m * 16 + fq * 4;
#pragma unroll
            for (int r = 0; r < 4; ++r) {
                int row = rb + r;
                if (row < mend) {
#pragma unroll
                    for (int n = 0; n < 4; ++n) {
                        int col = n0 + wc * 64 + n * 16 + fr;
                        float v = fmaxf(acc[m][n][r], 0.f);
                        H[(size_t)row * N_TOT + col] = f2bf(v);
                    }
                }
            }
        }
    } else {
        float* O = (float*)Cout;
#pragma unroll
        for (int m = 0; m < 4; ++m) {
            int rb = m0 + wr * 64 + m * 16 + fq * 4;
#pragma unroll
            for (int r = 0; r < 4; ++r) {
                int row = rb + r;
                if (row < mend) {
                    int   tkn = perm[row];
                    float cf  = coef[row];
#pragma unroll
                    for (int n = 0; n < 4; ++n) {
                        int col = n0 + wc * 64 + n * 16 + fr;
                        unsafeAtomicAdd(&O[(size_t)tkn * N_TOT + col], cf * acc[m][n][r]);
                    }
                }
            }
        }
    }
}

extern "C" void kernel_launch(void* const* d_in, const int* in_sizes, int n_in,
                              void* d_out, int out_size, void* d_ws, size_t ws_size,
                              hipStream_t stream) {
    const float* x  = (const float*)d_in[0];
    const float* Wg = (const float*)d_in[1];
    const float* bg = (const float*)d_in[2];
    const float* W1 = (const float*)d_in[3];
    const float* W2 = (const float*)d_in[4];

    char* ws = (char*)d_ws;
    int*   mi    = (int*)ws;
    float* mf    = (float*)(ws + 2048);
    int*   top1  = (int*)(ws + 4096);
    float* score = (float*)(ws + 36864);
    int*   perm  = (int*)(ws + 69632);
    float* coef  = (float*)(ws + 102400);
    unsigned short* Xg = (unsigned short*)(ws + 135168);     // 8192 x 1024 bf16
    unsigned short* H  = (unsigned short*)(ws + 16912384);   // 8192 x 4096 bf16
    unsigned short* Wt = (unsigned short*)(ws + 84021248);   // 8 x 4096 x 1024 bf16 (shared)

    // zero d_out: GEMM2 combines split-K halves with 2-way commutative atomic adds
    hipMemsetAsync(d_out, 0, (size_t)out_size * sizeof(float), stream);

    k_gate<<<dim3(T_TOK / 4), dim3(256), 0, stream>>>(x, Wg, bg, top1, score);
    k_meta<<<dim3(1), dim3(512), 0, stream>>>(top1, score, mi, mf);
    k_scatter<<<dim3(T_TOK / 256), dim3(256), 0, stream>>>(top1, score, mi, mf, perm, coef);
    k_gatherX<<<dim3(T_TOK * 128 / 256), dim3(256), 0, stream>>>(x, perm, Xg);

    // W1: [8][1024][4096] f32 -> Wt [8][4096][1024] bf16
    k_transp<<<dim3(N_INNER / 64, D_DIM / 64, NEXP), dim3(256), 0, stream>>>(W1, Wt, D_DIM, N_INNER);
    // H = relu(Xg @ W1t), K=1024 (NT=32).  Grid: 8 xcd x 4 n x 72 ti = 2304 blocks.
    k_moe_gemm<0><<<dim3(2304), dim3(256), 0, stream>>>(
        Xg, Wt, (void*)H, mi, perm, coef, D_DIM, N_INNER, 32);
    // W2: [8][4096][1024] f32 -> Wt [8][1024][4096] bf16
    k_transp<<<dim3(D_DIM / 64, N_INNER / 64, NEXP), dim3(256), 0, stream>>>(W2, Wt, N_INNER, D_DIM);
    // out += coef * (H @ W2t), split-K 2 (NT=64 per half).  Grid: 8 xcd x 2 g x 72 ti = 1152.
    k_moe_gemm<1><<<dim3(1152), dim3(256), 0, stream>>>(
        H, Wt, d_out, mi, perm, coef, N_INNER, D_DIM, 64);
}